// Round 1
// 624.468 us; speedup vs baseline: 1.0778x; 1.0778x over previous
//
#include <hip/hip_runtime.h>
#include <hip/hip_bf16.h>

// ResidualVQVAE forward, FP32 in / FP32 out.
// R9: k_vq_argmin LDS stage removed -- codebook pre-swizzled to MFMA B-fragment
// layout by ebook, read directly through L1/L2 (chunk = 128 KB, L2-resident;
// 4 waves/block share tiles in L1). Barrier-free, ping-pong register prefetch,
// setprio around MFMA clusters. MFMA/compare order bit-identical to R8.
// Launch fusion: ebook(m+1) folded into update(m); k_di folded into update<LAST>;
// all prep (6x swz + xsplit + bnprep) in one kernel. 39 -> 24 dispatches.

typedef __bf16 bf16x8 __attribute__((ext_vector_type(8)));
typedef float  f32x4  __attribute__((ext_vector_type(4)));

#define MFMA16(a,b,c) __builtin_amdgcn_mfma_f32_16x16x32_bf16((a),(b),(c),0,0,0)

__device__ __forceinline__ float b2f(ushort u){ return __uint_as_float(((unsigned)u) << 16); }
__device__ __forceinline__ ushort f2b_rne(float x){
  unsigned u = __float_as_uint(x);
  return (ushort)((u + 0x7fffu + ((u >> 16) & 1u)) >> 16);
}

// ---------------- prep device bodies ------------------------------------------------------
__device__ __forceinline__ void swz_body(const float* __restrict__ Wm, ushort* __restrict__ Wfh,
                                         ushort* __restrict__ Wfl, int N, int b){
  int gid = b * 256 + threadIdx.x;          // all weights are 32768 elems (128 blocks)
  int k = gid / N, n = gid - k * N;
  int kt = k >> 5, kr = k & 31, nt = n >> 4, nr = n & 15;
  int lane = (kr >> 3) * 16 + nr, tt = kr & 7;
  int o = (((kt * (N >> 4)) + nt) * 64 + lane) * 8 + tt;
  float v = Wm[gid];
  ushort h = f2b_rne(v);
  Wfh[o] = h;
  if (Wfl) Wfl[o] = f2b_rne(v - b2f(h));
}

__device__ __forceinline__ void bnprep_body(
    const float* g1,const float* be1,const float* rm1,const float* rv1,
    const float* g2,const float* be2,const float* rm2,const float* rv2,
    const float* g3,const float* be3,const float* rm3,const float* rv3,
    const float* g4,const float* be4,const float* rm4,const float* rv4,
    float* s1,float* t1,float* s2,float* t2,
    float* s3,float* t3,float* s4,float* t4)
{
  int t = threadIdx.x;
  if (t < 128){
    float sa = g1[t] / sqrtf(rv1[t] + 1e-5f);
    s1[t] = sa; t1[t] = be1[t] - rm1[t] * sa;
    float sb = g4[t] / sqrtf(rv4[t] + 1e-5f);
    s4[t] = sb; t4[t] = be4[t] - rm4[t] * sb;
  }
  if (t < 256){
    float sa = g2[t] / sqrtf(rv2[t] + 1e-5f);
    s2[t] = sa; t2[t] = be2[t] - rm2[t] * sa;
    float sb = g3[t] / sqrtf(rv3[t] + 1e-5f);
    s3[t] = sb; t3[t] = be3[t] - rm3[t] * sb;
  }
}

// ---------------- fused prep: 6x weight swizzle + x split + bn scale/shift ----------------
__global__ __launch_bounds__(256) void k_prep(
    const float* __restrict__ W1, const float* __restrict__ W2, const float* __restrict__ W3,
    const float* __restrict__ W4, const float* __restrict__ W5, const float* __restrict__ W6,
    ushort* W1fh, ushort* W1fl, ushort* W2fh, ushort* W2fl, ushort* W3fh, ushort* W3fl,
    ushort* W4fh, ushort* W5fh, ushort* W6fh,
    const float* __restrict__ x, ushort* __restrict__ xhi, ushort* __restrict__ xlo,
    const float* g1,const float* be1,const float* rm1,const float* rv1,
    const float* g2,const float* be2,const float* rm2,const float* rv2,
    const float* g3,const float* be3,const float* rm3,const float* rv3,
    const float* g4,const float* be4,const float* rm4,const float* rv4,
    float* s1,float* t1,float* s2,float* t2,float* s3,float* t3,float* s4,float* t4)
{
  int b = blockIdx.x;
  if (b < 768){
    if      (b < 128) swz_body(W1, W1fh, W1fl, 128, b);
    else if (b < 256) swz_body(W2, W2fh, W2fl, 256, b - 128);
    else if (b < 384) swz_body(W3, W3fh, W3fl, 128, b - 256);
    else if (b < 512) swz_body(W4, W4fh, nullptr, 256, b - 384);
    else if (b < 640) swz_body(W5, W5fh, nullptr, 128, b - 512);
    else              swz_body(W6, W6fh, nullptr, 256, b - 640);
  } else if (b < 8960){
    int i = (b - 768) * 256 + threadIdx.x;   // 8192x256 fp32 x
    float v = x[i];
    ushort h = f2b_rne(v);
    xhi[i] = h;
    xlo[i] = f2b_rne(v - b2f(h));
  } else {
    bnprep_body(g1,be1,rm1,rv1, g2,be2,rm2,rv2, g3,be3,rm3,rv3, g4,be4,rm4,rv4,
                s1,t1,s2,t2,s3,t3,s4,t4);
  }
}

// ---------------- per-book: codebook -> bf16 MFMA B-fragment layout + half-norms ----------
// Fragment layout (matches k_gemm B): for code group g=code>>4, ks=dim>>5:
//   Eb[((g*4+ks)*64 + qd*16 + c16)*8 + t], qd=(dim>>3)&3, t=dim&7, c16=code&15.
// argmin's per-wave fragment load is then one contiguous 1 KB global_load_dwordx4.
__device__ __forceinline__ void ebook_body(const float* __restrict__ Ef, ushort* __restrict__ Eb,
                                           float* __restrict__ hen, int code, int L){
  float2 e2 = *(const float2*)(Ef + code * 128 + L * 2);
  ushort h0 = f2b_rne(e2.x), h1 = f2b_rne(e2.y);
  int d = L * 2;
  int o = ((((code >> 4) * 4 + (d >> 5)) * 4 + ((d >> 3) & 3)) * 16 + (code & 15)) * 8 + (d & 7);
  *(unsigned*)(Eb + o) = (unsigned)h0 | ((unsigned)h1 << 16);
  float eh0 = b2f(h0), eh1 = b2f(h1);
  float s = eh0 * eh0 + eh1 * eh1;
  #pragma unroll
  for (int mask = 1; mask <= 32; mask <<= 1) s += __shfl_xor(s, mask);
  if (L == 0) hen[code] = 0.5f * s;
}

__global__ __launch_bounds__(256) void k_ebook(const float* __restrict__ Ef,
                                               ushort* __restrict__ Eb, float* __restrict__ hen){
  ebook_body(Ef, Eb, hen, blockIdx.x * 4 + (threadIdx.x >> 6), threadIdx.x & 63);
}

// ---------------- generic small GEMM: act(bn(A@B + bias)), A split hi/lo, B hi(+lo) -------
template<int NN, int KK, bool HAS_BLO, bool HAS_BN, bool HAS_RELU, int OUT_MODE>
__global__ __launch_bounds__(64) void k_gemm(
    const ushort* __restrict__ Ahi, const ushort* __restrict__ Alo,
    const ushort* __restrict__ Bfh, const ushort* __restrict__ Bfl,
    const float* __restrict__ bias,
    const float* __restrict__ bns,  const float* __restrict__ bnt,
    ushort* __restrict__ Ohi, ushort* __restrict__ Olo,
    float* __restrict__ Of32, float* __restrict__ Oz)
{
  constexpr int KS = KK / 32, CT = NN / 16;
  int L = threadIdx.x;
  int qd = L >> 4, c16 = L & 15;
  int row0 = blockIdx.x * 16;

  bf16x8 ah[KS], al[KS];
  #pragma unroll
  for (int ks = 0; ks < KS; ks++){
    int off = (row0 + c16) * KK + ks * 32 + qd * 8;
    ah[ks] = *(const bf16x8*)(Ahi + off);
    al[ks] = *(const bf16x8*)(Alo + off);
  }
  #pragma unroll
  for (int ct = 0; ct < CT; ct++){
    f32x4 acc = {0.f, 0.f, 0.f, 0.f};
    #pragma unroll
    for (int ks = 0; ks < KS; ks++){
      int bo = ((ks * CT + ct) * 64 + L) * 8;
      bf16x8 bh = *(const bf16x8*)(Bfh + bo);
      acc = MFMA16(ah[ks], bh, acc);
      acc = MFMA16(al[ks], bh, acc);
      if constexpr (HAS_BLO){
        bf16x8 bl = *(const bf16x8*)(Bfl + bo);
        acc = MFMA16(ah[ks], bl, acc);
      }
    }
    int col = ct * 16 + c16;
    float bia = bias[col];
    float s = 0.f, t = 0.f;
    if constexpr (HAS_BN){ s = bns[col]; t = bnt[col]; }
    #pragma unroll
    for (int i = 0; i < 4; i++){
      int row = row0 + qd * 4 + i;
      float v = acc[i] + bia;
      if constexpr (HAS_BN) v = v * s + t;
      if constexpr (HAS_RELU) v = fmaxf(v, 0.f);
      int o = row * NN + col;
      if constexpr (OUT_MODE == 2){
        Of32[o] = v;
      } else {
        ushort h = f2b_rne(v);
        Ohi[o] = h;
        Olo[o] = f2b_rne(v - b2f(h));
        if constexpr (OUT_MODE == 1){ Of32[o] = v; Oz[o] = 0.f; }
      }
    }
  }
}

// ---------------- VQ: fused distance + argmax(r.e - 0.5||e||^2), direct-from-L1/L2 --------
// grid: 64 row-blocks (128 rows) x 16 chunks (512 codes = 32 groups of 16).
// Per wave: 32 resident rows hi/lo; B-fragments read straight from the pre-swizzled
// codebook (contiguous 1 KB per load, L2-resident chunk, L1-shared across the block's
// 4 waves). No LDS, no barriers; 2-deep ping-pong prefetch; setprio around MFMA.
// MFMA chain + compare order identical to R8 -> bit-exact indices.
__global__ __launch_bounds__(256, 4) void k_vq_argmin(
  const ushort* __restrict__ Rhi, const ushort* __restrict__ Rlo,
  const ushort* __restrict__ Eb, const float* __restrict__ hen,
  float* __restrict__ cq, int* __restrict__ cj)
{
  int rb = blockIdx.x & 63, ch = blockIdx.x >> 6;
  int tid = threadIdx.x;
  int wv = tid >> 6, L = tid & 63;
  int qd = L >> 4, c16 = L & 15;
  int row0 = rb * 128 + wv * 32;

  // resident A fragments: 32 rows hi+lo (64 VGPRs)
  bf16x8 ah[2][4], al[2][4];
  #pragma unroll
  for (int t = 0; t < 2; t++){
    int r = row0 + t * 16 + c16;
    #pragma unroll
    for (int ks = 0; ks < 4; ks++){
      ah[t][ks] = *(const bf16x8*)(Rhi + r * 128 + ks * 32 + qd * 8);
      al[t][ks] = *(const bf16x8*)(Rlo + r * 128 + ks * 32 + qd * 8);
    }
  }
  float best[2][4]; int bj[2][4];
  #pragma unroll
  for (int t = 0; t < 2; t++)
    #pragma unroll
    for (int i = 0; i < 4; i++){ best[t][i] = -3.0e38f; bj[t][i] = 0; }

  const ushort* eb = Eb + (size_t)ch * 65536 + L * 8;   // chunk base, frag layout
  const float*  hb = hen + ch * 512 + c16;
  int jb = ch * 512 + c16;

  bf16x8 bA0 = *(const bf16x8*)(eb + 0 * 512);
  bf16x8 bA1 = *(const bf16x8*)(eb + 1 * 512);
  bf16x8 bA2 = *(const bf16x8*)(eb + 2 * 512);
  bf16x8 bA3 = *(const bf16x8*)(eb + 3 * 512);
  float hA = hb[0];

  #pragma unroll 1
  for (int g = 0; g < 32; g += 2){
    // prefetch group g+1 while computing g
    const ushort* ebB = eb + (g + 1) * 2048;
    bf16x8 bB0 = *(const bf16x8*)(ebB + 0 * 512);
    bf16x8 bB1 = *(const bf16x8*)(ebB + 1 * 512);
    bf16x8 bB2 = *(const bf16x8*)(ebB + 2 * 512);
    bf16x8 bB3 = *(const bf16x8*)(ebB + 3 * 512);
    float hB = hb[(g + 1) * 16];

    int jc = jb + g * 16;
    #pragma unroll
    for (int tt = 0; tt < 2; tt++){
      f32x4 acc = {0.f, 0.f, 0.f, 0.f};
      __builtin_amdgcn_s_setprio(1);
      acc = MFMA16(ah[tt][0], bA0, acc); acc = MFMA16(al[tt][0], bA0, acc);
      acc = MFMA16(ah[tt][1], bA1, acc); acc = MFMA16(al[tt][1], bA1, acc);
      acc = MFMA16(ah[tt][2], bA2, acc); acc = MFMA16(al[tt][2], bA2, acc);
      acc = MFMA16(ah[tt][3], bA3, acc); acc = MFMA16(al[tt][3], bA3, acc);
      __builtin_amdgcn_s_setprio(0);
      #pragma unroll
      for (int i = 0; i < 4; i++){
        float qv = acc[i] - hA;
        if (qv > best[tt][i]){ best[tt][i] = qv; bj[tt][i] = jc; }
      }
    }

    // prefetch group g+2 while computing g+1
    if (g + 2 < 32){
      const ushort* ebA = eb + (g + 2) * 2048;
      bA0 = *(const bf16x8*)(ebA + 0 * 512);
      bA1 = *(const bf16x8*)(ebA + 1 * 512);
      bA2 = *(const bf16x8*)(ebA + 2 * 512);
      bA3 = *(const bf16x8*)(ebA + 3 * 512);
      hA = hb[(g + 2) * 16];
    }
    jc = jb + (g + 1) * 16;
    #pragma unroll
    for (int tt = 0; tt < 2; tt++){
      f32x4 acc = {0.f, 0.f, 0.f, 0.f};
      __builtin_amdgcn_s_setprio(1);
      acc = MFMA16(ah[tt][0], bB0, acc); acc = MFMA16(al[tt][0], bB0, acc);
      acc = MFMA16(ah[tt][1], bB1, acc); acc = MFMA16(al[tt][1], bB1, acc);
      acc = MFMA16(ah[tt][2], bB2, acc); acc = MFMA16(al[tt][2], bB2, acc);
      acc = MFMA16(ah[tt][3], bB3, acc); acc = MFMA16(al[tt][3], bB3, acc);
      __builtin_amdgcn_s_setprio(0);
      #pragma unroll
      for (int i = 0; i < 4; i++){
        float qv = acc[i] - hB;
        if (qv > best[tt][i]){ best[tt][i] = qv; bj[tt][i] = jc; }
      }
    }
  }

  // cross-lane reduce over the 16 code-columns, ties -> smaller j
  #pragma unroll
  for (int mask = 1; mask <= 8; mask <<= 1){
    #pragma unroll
    for (int t = 0; t < 2; t++)
      #pragma unroll
      for (int i = 0; i < 4; i++){
        float ob = __shfl_xor(best[t][i], mask);
        int   oj = __shfl_xor(bj[t][i], mask);
        if (ob > best[t][i] || (ob == best[t][i] && oj < bj[t][i])){ best[t][i] = ob; bj[t][i] = oj; }
      }
  }
  if (c16 == 0){
    #pragma unroll
    for (int t = 0; t < 2; t++)
      #pragma unroll
      for (int i = 0; i < 4; i++){
        int r = row0 + t * 16 + qd * 4 + i;
        cq[r * 16 + ch] = best[t][i];
        cj[r * 16 + ch] = bj[t][i];
      }
  }
}

// ---------------- VQ: combine chunk candidates, emit res_s/ce_s, update, + next ebook -----
// LAST: rhi/rlo get split(zq+ce) (k_di folded in); res/zq stores skipped (dead after).
// !LAST: also converts the NEXT book's codebook (Eb consumed by argmin(m) already).
template<bool LAST>
__global__ __launch_bounds__(256) void k_vq_update(
  const float* __restrict__ cq, const int* __restrict__ cj,
  const float* __restrict__ Ef, const float* __restrict__ Efn,
  ushort* __restrict__ Eb, float* __restrict__ hen,
  float* __restrict__ res, float* __restrict__ zq,
  ushort* __restrict__ rhi, ushort* __restrict__ rlo,
  float* __restrict__ res_s, float* __restrict__ ce_s)
{
  int idx = blockIdx.x * 4 + (threadIdx.x >> 6);
  int L = threadIdx.x & 63;
  int c = L & 15;
  float bq = cq[idx * 16 + c]; int bi = cj[idx * 16 + c];
  #pragma unroll
  for (int mask = 1; mask <= 8; mask <<= 1){
    float ob = __shfl_xor(bq, mask);
    int   oj = __shfl_xor(bi, mask);
    if (ob > bq || (ob == bq && oj < bi)){ bq = ob; bi = oj; }
  }
  int o = idx * 128 + L * 2;
  float2 ce = *(const float2*)(Ef + bi * 128 + L * 2);   // fp32 codebook row
  float2 r2 = *(const float2*)(res + o);
  *(float2*)(res_s + o) = r2;
  *(float2*)(ce_s + o) = ce;
  float rn0 = r2.x - ce.x, rn1 = r2.y - ce.y;
  float z0 = zq[o] + ce.x, z1 = zq[o + 1] + ce.y;
  float o0, o1;
  if constexpr (LAST){
    o0 = z0; o1 = z1;                 // di = zq (STE forward)
  } else {
    res[o] = rn0; res[o + 1] = rn1;
    zq[o] = z0;   zq[o + 1] = z1;
    o0 = rn0; o1 = rn1;
  }
  ushort h0 = f2b_rne(o0), h1 = f2b_rne(o1);
  *(unsigned*)(rhi + o) = (unsigned)h0 | ((unsigned)h1 << 16);
  ushort l0 = f2b_rne(o0 - b2f(h0)), l1 = f2b_rne(o1 - b2f(h1));
  *(unsigned*)(rlo + o) = (unsigned)l0 | ((unsigned)l1 << 16);
  if constexpr (!LAST) ebook_body(Efn, Eb, hen, idx, L);
}

extern "C" void kernel_launch(void* const* d_in, const int* in_sizes, int n_in,
                              void* d_out, int out_size, void* d_ws, size_t ws_size,
                              hipStream_t stream)
{
  const float* x   = (const float*)d_in[0];
  const float* W1  = (const float*)d_in[1];
  const float* b1  = (const float*)d_in[2];
  const float* g1  = (const float*)d_in[3];
  const float* be1 = (const float*)d_in[4];
  const float* rm1 = (const float*)d_in[5];
  const float* rv1 = (const float*)d_in[6];
  const float* W2  = (const float*)d_in[7];
  const float* b2  = (const float*)d_in[8];
  const float* g2  = (const float*)d_in[9];
  const float* be2 = (const float*)d_in[10];
  const float* rm2 = (const float*)d_in[11];
  const float* rv2 = (const float*)d_in[12];
  const float* W3  = (const float*)d_in[13];
  const float* b3  = (const float*)d_in[14];
  const float* CB  = (const float*)d_in[15];
  const float* W4  = (const float*)d_in[16];
  const float* b4  = (const float*)d_in[17];
  const float* g3  = (const float*)d_in[18];
  const float* be3 = (const float*)d_in[19];
  const float* rm3 = (const float*)d_in[20];
  const float* rv3 = (const float*)d_in[21];
  const float* W5  = (const float*)d_in[22];
  const float* b5  = (const float*)d_in[23];
  const float* g4  = (const float*)d_in[24];
  const float* be4 = (const float*)d_in[25];
  const float* rm4 = (const float*)d_in[26];
  const float* rv4 = (const float*)d_in[27];
  const float* W6  = (const float*)d_in[28];
  const float* b6  = (const float*)d_in[29];

  char* w = (char*)d_ws;                       // total ~24.6 MiB
  // Eb + cq/cj alias the h1 region (dead during VQ; decoder GEMM-2 rewrites h1 after).
  ushort* Eb   = (ushort*)(w + 0);             // per-book bf16 codebook (frag layout), 2 MiB
  float*  cq   = (float*) (w + 2097152);       // 8192x16, 512 KiB
  int*    cj   = (int*)   (w + 2621440);       // 8192x16, 512 KiB (ends 3 MiB < 4 MiB)
  ushort* h1hi = (ushort*)(w + 0);             // 8192x128 bf16, 2 MiB
  ushort* h1lo = (ushort*)(w + 2097152);       // 2 MiB
  ushort* h2hi = (ushort*)(w + 4194304);       // 8192x256 bf16, 4 MiB
  ushort* h2lo = (ushort*)(w + 8388608);       // 4 MiB
  ushort* rhi  = (ushort*)(w + 12582912);      // residual split, 2 MiB
  ushort* rlo  = (ushort*)(w + 14680064);      // 2 MiB
  // res/zq alias xhi/xlo (x consumed by enc GEMM-1 before res/zq written).
  ushort* xhi  = (ushort*)(w + 16777216);      // 4 MiB
  ushort* xlo  = (ushort*)(w + 20971520);      // 4 MiB
  float*  res  = (float*) (w + 16777216);
  float*  zq   = (float*) (w + 20971520);
  float*  hen  = (float*) (w + 25165824);      // per-book half-norms, 32 KiB
  float*  s1   = (float*) (w + 25198592);
  float*  t1   = (float*) (w + 25199104);
  float*  s2   = (float*) (w + 25199616);
  float*  t2   = (float*) (w + 25200640);
  float*  s3   = (float*) (w + 25201664);
  float*  t3   = (float*) (w + 25202688);
  float*  s4   = (float*) (w + 25203712);
  float*  t4   = (float*) (w + 25204224);
  ushort* W1fh = (ushort*)(w + 25204736);
  ushort* W2fh = (ushort*)(w + 25270272);
  ushort* W3fh = (ushort*)(w + 25335808);
  ushort* W4fh = (ushort*)(w + 25401344);
  ushort* W5fh = (ushort*)(w + 25466880);
  ushort* W6fh = (ushort*)(w + 25532416);
  ushort* W1fl = (ushort*)(w + 25597952);
  ushort* W2fl = (ushort*)(w + 25663488);
  ushort* W3fl = (ushort*)(w + 25729024);      // end ~24.6 MiB

  float* xhat  = (float*)d_out;                // [8192,256] fp32
  float* res_s = xhat + 2097152;               // [8,8192,128] fp32
  float* ce_s  = res_s + 8388608;              // [8,8192,128] fp32

  // fused prep: weights -> frag layout, x -> hi/lo split, BN fold
  k_prep<<<8961, 256, 0, stream>>>(W1, W2, W3, W4, W5, W6,
                                   W1fh, W1fl, W2fh, W2fl, W3fh, W3fl,
                                   W4fh, W5fh, W6fh,
                                   x, xhi, xlo,
                                   g1,be1,rm1,rv1, g2,be2,rm2,rv2,
                                   g3,be3,rm3,rv3, g4,be4,rm4,rv4,
                                   s1,t1,s2,t2,s3,t3,s4,t4);

  // encoder
  k_gemm<128,256,true,true,true,0><<<512,64,0,stream>>>(xhi, xlo, W1fh, W1fl, b1, s1, t1, h1hi, h1lo, nullptr, nullptr);
  k_gemm<256,128,true,true,true,0><<<512,64,0,stream>>>(h1hi, h1lo, W2fh, W2fl, b2, s2, t2, h2hi, h2lo, nullptr, nullptr);
  k_gemm<128,256,true,false,false,1><<<512,64,0,stream>>>(h2hi, h2lo, W3fh, W3fl, b3, nullptr, nullptr, rhi, rlo, res, zq);

  // residual VQ over 8 books (ebook for book m+1 fused into update(m))
  k_ebook<<<2048, 256, 0, stream>>>(CB, Eb, hen);
  for (int m = 0; m < 8; m++){
    const float* Ef = CB + (size_t)m * 1048576;
    k_vq_argmin<<<1024, 256, 0, stream>>>(rhi, rlo, Eb, hen, cq, cj);
    if (m < 7){
      k_vq_update<false><<<2048, 256, 0, stream>>>(cq, cj, Ef, Ef + 1048576, Eb, hen,
                                                   res, zq, rhi, rlo,
                                                   res_s + (size_t)m * 1048576,
                                                   ce_s  + (size_t)m * 1048576);
    } else {
      k_vq_update<true><<<2048, 256, 0, stream>>>(cq, cj, Ef, nullptr, Eb, hen,
                                                  res, zq, rhi, rlo,
                                                  res_s + (size_t)m * 1048576,
                                                  ce_s  + (size_t)m * 1048576);
    }
  }

  // decoder (rhi/rlo hold split(di) from update<LAST>)
  k_gemm<256,128,false,true,true,0><<<512,64,0,stream>>>(rhi, rlo, W4fh, nullptr, b4, s3, t3, h2hi, h2lo, nullptr, nullptr);
  k_gemm<128,256,false,true,true,0><<<512,64,0,stream>>>(h2hi, h2lo, W5fh, nullptr, b5, s4, t4, h1hi, h1lo, nullptr, nullptr);
  k_gemm<256,128,false,false,false,2><<<512,64,0,stream>>>(h1hi, h1lo, W6fh, nullptr, b6, nullptr, nullptr, nullptr, nullptr, xhat, nullptr);
}

// Round 2
// 534.962 us; speedup vs baseline: 1.2581x; 1.1673x over previous
//
#include <hip/hip_runtime.h>
#include <hip/hip_bf16.h>

// ResidualVQVAE forward, FP32 in / FP32 out.
// R10: (a) k_vq_argmin B-prefetch at half-group granularity -> ~118 VGPRs, fits
// 4 waves/SIMD at launch_bounds(256,4) without spill; per-acc MFMA order unchanged
// (bit-exact vs R8/R9). (b) encoder / decoder each fused into ONE kernel (row-local
// since BN is eval-mode): 16 rows/block, 4 waves ct-split, fp32 LDS staging between
// layers (pad-4 stride -> 2-way-free banks), hi/lo conversion at stage-read identical
// to old global round-trip. x-split folded into encoder. 24 -> 20 dispatches.

typedef __bf16 bf16x8 __attribute__((ext_vector_type(8)));
typedef float  f32x4  __attribute__((ext_vector_type(4)));
typedef unsigned short ushort8v __attribute__((ext_vector_type(8)));

#define MFMA16(a,b,c) __builtin_amdgcn_mfma_f32_16x16x32_bf16((a),(b),(c),0,0,0)

__device__ __forceinline__ float b2f(ushort u){ return __uint_as_float(((unsigned)u) << 16); }
__device__ __forceinline__ ushort f2b_rne(float x){
  unsigned u = __float_as_uint(x);
  return (ushort)((u + 0x7fffu + ((u >> 16) & 1u)) >> 16);
}

// convert 8 consecutive fp32 -> bf16 hi/lo fragment pair (bit-identical to the old
// k_xsplit / k_gemm-epilogue path: h = rne(v), l = rne(v - b2f(h)))
__device__ __forceinline__ void cvt8(const float* p, bf16x8& h8, bf16x8& l8){
  f32x4 v0 = *(const f32x4*)p;
  f32x4 v1 = *(const f32x4*)(p + 4);
  ushort8v uh, ul;
  #pragma unroll
  for (int i = 0; i < 4; i++){
    float a = v0[i]; ushort h = f2b_rne(a); uh[i] = h;     ul[i]     = f2b_rne(a - b2f(h));
    float b = v1[i]; ushort g = f2b_rne(b); uh[i + 4] = g; ul[i + 4] = f2b_rne(b - b2f(g));
  }
  h8 = __builtin_bit_cast(bf16x8, uh);
  l8 = __builtin_bit_cast(bf16x8, ul);
}

// one 16x16 output-column-tile dot product, identical MFMA chain to old k_gemm
template<int KK, int NN, bool HAS_BLO>
__device__ __forceinline__ f32x4 dotct(const bf16x8* ah, const bf16x8* al,
                                       const ushort* __restrict__ Bfh,
                                       const ushort* __restrict__ Bfl,
                                       int ct, int L){
  constexpr int KS = KK / 32, CT = NN / 16;
  f32x4 acc = {0.f, 0.f, 0.f, 0.f};
  #pragma unroll
  for (int ks = 0; ks < KS; ks++){
    int bo = ((ks * CT + ct) * 64 + L) * 8;
    bf16x8 bh = *(const bf16x8*)(Bfh + bo);
    acc = MFMA16(ah[ks], bh, acc);
    acc = MFMA16(al[ks], bh, acc);
    if constexpr (HAS_BLO){
      bf16x8 bl = *(const bf16x8*)(Bfl + bo);
      acc = MFMA16(ah[ks], bl, acc);
    }
  }
  return acc;
}

// ---------------- prep: weight swizzle + BN fold ------------------------------------------
__device__ __forceinline__ void swz_body(const float* __restrict__ Wm, ushort* __restrict__ Wfh,
                                         ushort* __restrict__ Wfl, int N, int b){
  int gid = b * 256 + threadIdx.x;          // all weights are 32768 elems (128 blocks)
  int k = gid / N, n = gid - k * N;
  int kt = k >> 5, kr = k & 31, nt = n >> 4, nr = n & 15;
  int lane = (kr >> 3) * 16 + nr, tt = kr & 7;
  int o = (((kt * (N >> 4)) + nt) * 64 + lane) * 8 + tt;
  float v = Wm[gid];
  ushort h = f2b_rne(v);
  Wfh[o] = h;
  if (Wfl) Wfl[o] = f2b_rne(v - b2f(h));
}

__global__ __launch_bounds__(256) void k_prep(
    const float* __restrict__ W1, const float* __restrict__ W2, const float* __restrict__ W3,
    const float* __restrict__ W4, const float* __restrict__ W5, const float* __restrict__ W6,
    ushort* W1fh, ushort* W1fl, ushort* W2fh, ushort* W2fl, ushort* W3fh, ushort* W3fl,
    ushort* W4fh, ushort* W5fh, ushort* W6fh,
    const float* g1,const float* be1,const float* rm1,const float* rv1,
    const float* g2,const float* be2,const float* rm2,const float* rv2,
    const float* g3,const float* be3,const float* rm3,const float* rv3,
    const float* g4,const float* be4,const float* rm4,const float* rv4,
    float* s1,float* t1,float* s2,float* t2,float* s3,float* t3,float* s4,float* t4)
{
  int b = blockIdx.x;
  if (b < 768){
    if      (b < 128) swz_body(W1, W1fh, W1fl, 128, b);
    else if (b < 256) swz_body(W2, W2fh, W2fl, 256, b - 128);
    else if (b < 384) swz_body(W3, W3fh, W3fl, 128, b - 256);
    else if (b < 512) swz_body(W4, W4fh, nullptr, 256, b - 384);
    else if (b < 640) swz_body(W5, W5fh, nullptr, 128, b - 512);
    else              swz_body(W6, W6fh, nullptr, 256, b - 640);
  } else {
    int t = threadIdx.x;
    if (t < 128){
      float sa = g1[t] / sqrtf(rv1[t] + 1e-5f);
      s1[t] = sa; t1[t] = be1[t] - rm1[t] * sa;
      float sb = g4[t] / sqrtf(rv4[t] + 1e-5f);
      s4[t] = sb; t4[t] = be4[t] - rm4[t] * sb;
    }
    if (t < 256){
      float sa = g2[t] / sqrtf(rv2[t] + 1e-5f);
      s2[t] = sa; t2[t] = be2[t] - rm2[t] * sa;
      float sb = g3[t] / sqrtf(rv3[t] + 1e-5f);
      s3[t] = sb; t3[t] = be3[t] - rm3[t] * sb;
    }
  }
}

// ---------------- fused encoder: x -> (bn relu gemm)x2 -> gemm -> res/zq/rhi/rlo ----------
// 16 rows/block, 4 waves split output col-tiles; fp32 LDS staging between layers.
__global__ __launch_bounds__(256) void k_encoder(
    const float* __restrict__ x,
    const ushort* __restrict__ W1fh, const ushort* __restrict__ W1fl,
    const ushort* __restrict__ W2fh, const ushort* __restrict__ W2fl,
    const ushort* __restrict__ W3fh, const ushort* __restrict__ W3fl,
    const float* __restrict__ b1, const float* __restrict__ s1, const float* __restrict__ t1,
    const float* __restrict__ b2, const float* __restrict__ s2, const float* __restrict__ t2,
    const float* __restrict__ b3,
    ushort* __restrict__ rhi, ushort* __restrict__ rlo,
    float* __restrict__ res, float* __restrict__ zq)
{
  __shared__ __align__(16) float sA[16 * 260];   // 16 x 256 stage (+4 pad)
  __shared__ __align__(16) float sB[16 * 132];   // 16 x 128 stage (+4 pad)
  int tid = threadIdx.x;
  int wv = tid >> 6, L = tid & 63;
  int qd = L >> 4, c16 = L & 15;
  int row0 = blockIdx.x * 16;

  // A1 from x fp32 (split in-kernel, bit-identical to k_xsplit)
  bf16x8 a1h[8], a1l[8];
  #pragma unroll
  for (int ks = 0; ks < 8; ks++)
    cvt8(x + (row0 + c16) * 256 + ks * 32 + qd * 8, a1h[ks], a1l[ks]);

  // layer 1: 256 -> 128, bn relu -> sB
  #pragma unroll
  for (int u = 0; u < 2; u++){
    int ct = wv * 2 + u;
    f32x4 acc = dotct<256,128,true>(a1h, a1l, W1fh, W1fl, ct, L);
    int col = ct * 16 + c16;
    float bia = b1[col], sc = s1[col], sh = t1[col];
    #pragma unroll
    for (int i = 0; i < 4; i++){
      float v = (acc[i] + bia) * sc + sh;
      sB[(qd * 4 + i) * 132 + col] = fmaxf(v, 0.f);
    }
  }
  __syncthreads();

  // A2 from sB
  bf16x8 a2h[4], a2l[4];
  #pragma unroll
  for (int ks = 0; ks < 4; ks++)
    cvt8(sB + c16 * 132 + ks * 32 + qd * 8, a2h[ks], a2l[ks]);

  // layer 2: 128 -> 256, bn relu -> sA
  #pragma unroll
  for (int u = 0; u < 4; u++){
    int ct = wv * 4 + u;
    f32x4 acc = dotct<128,256,true>(a2h, a2l, W2fh, W2fl, ct, L);
    int col = ct * 16 + c16;
    float bia = b2[col], sc = s2[col], sh = t2[col];
    #pragma unroll
    for (int i = 0; i < 4; i++){
      float v = (acc[i] + bia) * sc + sh;
      sA[(qd * 4 + i) * 260 + col] = fmaxf(v, 0.f);
    }
  }
  __syncthreads();

  // A3 from sA
  bf16x8 a3h[8], a3l[8];
  #pragma unroll
  for (int ks = 0; ks < 8; ks++)
    cvt8(sA + c16 * 260 + ks * 32 + qd * 8, a3h[ks], a3l[ks]);

  // layer 3: 256 -> 128, bias only; emit res/zq fp32 + rhi/rlo split
  #pragma unroll
  for (int u = 0; u < 2; u++){
    int ct = wv * 2 + u;
    f32x4 acc = dotct<256,128,true>(a3h, a3l, W3fh, W3fl, ct, L);
    int col = ct * 16 + c16;
    float bia = b3[col];
    #pragma unroll
    for (int i = 0; i < 4; i++){
      int row = row0 + qd * 4 + i;
      float v = acc[i] + bia;
      int o = row * 128 + col;
      res[o] = v; zq[o] = 0.f;
      ushort h = f2b_rne(v);
      rhi[o] = h;
      rlo[o] = f2b_rne(v - b2f(h));
    }
  }
}

// ---------------- fused decoder: di -> (bn relu gemm)x2 -> gemm -> xhat -------------------
__global__ __launch_bounds__(256) void k_decoder(
    const ushort* __restrict__ dhi, const ushort* __restrict__ dlo,
    const ushort* __restrict__ W4fh, const ushort* __restrict__ W5fh,
    const ushort* __restrict__ W6fh,
    const float* __restrict__ b4, const float* __restrict__ s3, const float* __restrict__ t3,
    const float* __restrict__ b5, const float* __restrict__ s4, const float* __restrict__ t4,
    const float* __restrict__ b6,
    float* __restrict__ xhat)
{
  __shared__ __align__(16) float sA[16 * 260];
  __shared__ __align__(16) float sB[16 * 132];
  int tid = threadIdx.x;
  int wv = tid >> 6, L = tid & 63;
  int qd = L >> 4, c16 = L & 15;
  int row0 = blockIdx.x * 16;

  // A1 from pre-split di
  bf16x8 a1h[4], a1l[4];
  #pragma unroll
  for (int ks = 0; ks < 4; ks++){
    int off = (row0 + c16) * 128 + ks * 32 + qd * 8;
    a1h[ks] = *(const bf16x8*)(dhi + off);
    a1l[ks] = *(const bf16x8*)(dlo + off);
  }

  // layer 4: 128 -> 256, bn relu -> sA
  #pragma unroll
  for (int u = 0; u < 4; u++){
    int ct = wv * 4 + u;
    f32x4 acc = dotct<128,256,false>(a1h, a1l, W4fh, nullptr, ct, L);
    int col = ct * 16 + c16;
    float bia = b4[col], sc = s3[col], sh = t3[col];
    #pragma unroll
    for (int i = 0; i < 4; i++){
      float v = (acc[i] + bia) * sc + sh;
      sA[(qd * 4 + i) * 260 + col] = fmaxf(v, 0.f);
    }
  }
  __syncthreads();

  // A2 from sA
  bf16x8 a2h[8], a2l[8];
  #pragma unroll
  for (int ks = 0; ks < 8; ks++)
    cvt8(sA + c16 * 260 + ks * 32 + qd * 8, a2h[ks], a2l[ks]);

  // layer 5: 256 -> 128, bn relu -> sB
  #pragma unroll
  for (int u = 0; u < 2; u++){
    int ct = wv * 2 + u;
    f32x4 acc = dotct<256,128,false>(a2h, a2l, W5fh, nullptr, ct, L);
    int col = ct * 16 + c16;
    float bia = b5[col], sc = s4[col], sh = t4[col];
    #pragma unroll
    for (int i = 0; i < 4; i++){
      float v = (acc[i] + bia) * sc + sh;
      sB[(qd * 4 + i) * 132 + col] = fmaxf(v, 0.f);
    }
  }
  __syncthreads();

  // A3 from sB
  bf16x8 a3h[4], a3l[4];
  #pragma unroll
  for (int ks = 0; ks < 4; ks++)
    cvt8(sB + c16 * 132 + ks * 32 + qd * 8, a3h[ks], a3l[ks]);

  // layer 6: 128 -> 256, bias only -> xhat fp32
  #pragma unroll
  for (int u = 0; u < 4; u++){
    int ct = wv * 4 + u;
    f32x4 acc = dotct<128,256,false>(a3h, a3l, W6fh, nullptr, ct, L);
    int col = ct * 16 + c16;
    float bia = b6[col];
    #pragma unroll
    for (int i = 0; i < 4; i++)
      xhat[(row0 + qd * 4 + i) * 256 + col] = acc[i] + bia;
  }
}

// ---------------- per-book: codebook -> bf16 MFMA B-fragment layout + half-norms ----------
__device__ __forceinline__ void ebook_body(const float* __restrict__ Ef, ushort* __restrict__ Eb,
                                           float* __restrict__ hen, int code, int L){
  float2 e2 = *(const float2*)(Ef + code * 128 + L * 2);
  ushort h0 = f2b_rne(e2.x), h1 = f2b_rne(e2.y);
  int d = L * 2;
  int o = ((((code >> 4) * 4 + (d >> 5)) * 4 + ((d >> 3) & 3)) * 16 + (code & 15)) * 8 + (d & 7);
  *(unsigned*)(Eb + o) = (unsigned)h0 | ((unsigned)h1 << 16);
  float eh0 = b2f(h0), eh1 = b2f(h1);
  float s = eh0 * eh0 + eh1 * eh1;
  #pragma unroll
  for (int mask = 1; mask <= 32; mask <<= 1) s += __shfl_xor(s, mask);
  if (L == 0) hen[code] = 0.5f * s;
}

__global__ __launch_bounds__(256) void k_ebook(const float* __restrict__ Ef,
                                               ushort* __restrict__ Eb, float* __restrict__ hen){
  ebook_body(Ef, Eb, hen, blockIdx.x * 4 + (threadIdx.x >> 6), threadIdx.x & 63);
}

// ---------------- VQ: fused distance + argmax(r.e - 0.5||e||^2), direct-from-L1/L2 --------
// Half-group B prefetch: peak B live = 16 VGPRs (c0,c1,n0,n1); total ~118 VGPRs ->
// fits 4 waves/SIMD at launch_bounds(256,4) without spill. Per-acc MFMA order is the
// R8/R9 chain (ks0 hi,lo, ks1 hi,lo, ks2 hi,lo, ks3 hi,lo) -> bit-exact scores.
__global__ __launch_bounds__(256, 4) void k_vq_argmin(
  const ushort* __restrict__ Rhi, const ushort* __restrict__ Rlo,
  const ushort* __restrict__ Eb, const float* __restrict__ hen,
  float* __restrict__ cq, int* __restrict__ cj)
{
  int rb = blockIdx.x & 63, ch = blockIdx.x >> 6;
  int tid = threadIdx.x;
  int wv = tid >> 6, L = tid & 63;
  int qd = L >> 4, c16 = L & 15;
  int row0 = rb * 128 + wv * 32;

  // resident A fragments: 32 rows hi+lo (64 VGPRs)
  bf16x8 ah[2][4], al[2][4];
  #pragma unroll
  for (int t = 0; t < 2; t++){
    int r = row0 + t * 16 + c16;
    #pragma unroll
    for (int ks = 0; ks < 4; ks++){
      ah[t][ks] = *(const bf16x8*)(Rhi + r * 128 + ks * 32 + qd * 8);
      al[t][ks] = *(const bf16x8*)(Rlo + r * 128 + ks * 32 + qd * 8);
    }
  }
  float best[2][4]; int bj[2][4];
  #pragma unroll
  for (int t = 0; t < 2; t++)
    #pragma unroll
    for (int i = 0; i < 4; i++){ best[t][i] = -3.0e38f; bj[t][i] = 0; }

  const ushort* eb = Eb + (size_t)ch * 65536 + L * 8;   // chunk base, frag layout
  const float*  hb = hen + ch * 512 + c16;
  int jb = ch * 512 + c16;

  bf16x8 c0 = *(const bf16x8*)(eb + 0);
  bf16x8 c1 = *(const bf16x8*)(eb + 512);
  float hA = hb[0];

  #pragma unroll 1
  for (int g = 0; g < 32; ++g){
    const ushort* ebg = eb + g * 2048;
    // prefetch second half of this group
    bf16x8 n0 = *(const bf16x8*)(ebg + 1024);
    bf16x8 n1 = *(const bf16x8*)(ebg + 1536);
    int gn = (g + 1 < 32) ? g + 1 : 31;               // clamped (values unused at g=31)
    float hN = hb[gn * 16];

    f32x4 acc0 = {0.f, 0.f, 0.f, 0.f}, acc1 = {0.f, 0.f, 0.f, 0.f};
    __builtin_amdgcn_s_setprio(1);
    acc0 = MFMA16(ah[0][0], c0, acc0); acc0 = MFMA16(al[0][0], c0, acc0);
    acc0 = MFMA16(ah[0][1], c1, acc0); acc0 = MFMA16(al[0][1], c1, acc0);
    acc1 = MFMA16(ah[1][0], c0, acc1); acc1 = MFMA16(al[1][0], c0, acc1);
    acc1 = MFMA16(ah[1][1], c1, acc1); acc1 = MFMA16(al[1][1], c1, acc1);
    __builtin_amdgcn_s_setprio(0);
    // prefetch first half of the NEXT group (c0/c1 dead after the MFMAs above)
    const ushort* ebn = eb + gn * 2048;
    c0 = *(const bf16x8*)(ebn + 2048);
    c1 = *(const bf16x8*)(ebn + 2048 + 512);
    __builtin_amdgcn_s_setprio(1);
    acc0 = MFMA16(ah[0][2], n0, acc0); acc0 = MFMA16(al[0][2], n0, acc0);
    acc0 = MFMA16(ah[0][3], n1, acc0); acc0 = MFMA16(al[0][3], n1, acc0);
    acc1 = MFMA16(ah[1][2], n0, acc1); acc1 = MFMA16(al[1][2], n0, acc1);
    acc1 = MFMA16(ah[1][3], n1, acc1); acc1 = MFMA16(al[1][3], n1, acc1);
    __builtin_amdgcn_s_setprio(0);

    int jc = jb + g * 16;
    #pragma unroll
    for (int i = 0; i < 4; i++){
      float q0 = acc0[i] - hA;
      if (q0 > best[0][i]){ best[0][i] = q0; bj[0][i] = jc; }
      float q1 = acc1[i] - hA;
      if (q1 > best[1][i]){ best[1][i] = q1; bj[1][i] = jc; }
    }
    hA = hN;
  }

  // cross-lane reduce over the 16 code-columns, ties -> smaller j
  #pragma unroll
  for (int mask = 1; mask <= 8; mask <<= 1){
    #pragma unroll
    for (int t = 0; t < 2; t++)
      #pragma unroll
      for (int i = 0; i < 4; i++){
        float ob = __shfl_xor(best[t][i], mask);
        int   oj = __shfl_xor(bj[t][i], mask);
        if (ob > best[t][i] || (ob == best[t][i] && oj < bj[t][i])){ best[t][i] = ob; bj[t][i] = oj; }
      }
  }
  if (c16 == 0){
    #pragma unroll
    for (int t = 0; t < 2; t++)
      #pragma unroll
      for (int i = 0; i < 4; i++){
        int r = row0 + t * 16 + qd * 4 + i;
        cq[r * 16 + ch] = best[t][i];
        cj[r * 16 + ch] = bj[t][i];
      }
  }
}

// ---------------- VQ: combine chunk candidates, emit res_s/ce_s, update, + next ebook -----
template<bool LAST>
__global__ __launch_bounds__(256) void k_vq_update(
  const float* __restrict__ cq, const int* __restrict__ cj,
  const float* __restrict__ Ef, const float* __restrict__ Efn,
  ushort* __restrict__ Eb, float* __restrict__ hen,
  float* __restrict__ res, float* __restrict__ zq,
  ushort* __restrict__ rhi, ushort* __restrict__ rlo,
  float* __restrict__ res_s, float* __restrict__ ce_s)
{
  int idx = blockIdx.x * 4 + (threadIdx.x >> 6);
  int L = threadIdx.x & 63;
  int c = L & 15;
  float bq = cq[idx * 16 + c]; int bi = cj[idx * 16 + c];
  #pragma unroll
  for (int mask = 1; mask <= 8; mask <<= 1){
    float ob = __shfl_xor(bq, mask);
    int   oj = __shfl_xor(bi, mask);
    if (ob > bq || (ob == bq && oj < bi)){ bq = ob; bi = oj; }
  }
  int o = idx * 128 + L * 2;
  float2 ce = *(const float2*)(Ef + bi * 128 + L * 2);   // fp32 codebook row
  float2 r2 = *(const float2*)(res + o);
  *(float2*)(res_s + o) = r2;
  *(float2*)(ce_s + o) = ce;
  float rn0 = r2.x - ce.x, rn1 = r2.y - ce.y;
  float z0 = zq[o] + ce.x, z1 = zq[o + 1] + ce.y;
  float o0, o1;
  if constexpr (LAST){
    o0 = z0; o1 = z1;                 // di = zq (STE forward)
  } else {
    res[o] = rn0; res[o + 1] = rn1;
    zq[o] = z0;   zq[o + 1] = z1;
    o0 = rn0; o1 = rn1;
  }
  ushort h0 = f2b_rne(o0), h1 = f2b_rne(o1);
  *(unsigned*)(rhi + o) = (unsigned)h0 | ((unsigned)h1 << 16);
  ushort l0 = f2b_rne(o0 - b2f(h0)), l1 = f2b_rne(o1 - b2f(h1));
  *(unsigned*)(rlo + o) = (unsigned)l0 | ((unsigned)l1 << 16);
  if constexpr (!LAST) ebook_body(Efn, Eb, hen, idx, L);
}

extern "C" void kernel_launch(void* const* d_in, const int* in_sizes, int n_in,
                              void* d_out, int out_size, void* d_ws, size_t ws_size,
                              hipStream_t stream)
{
  const float* x   = (const float*)d_in[0];
  const float* W1  = (const float*)d_in[1];
  const float* b1  = (const float*)d_in[2];
  const float* g1  = (const float*)d_in[3];
  const float* be1 = (const float*)d_in[4];
  const float* rm1 = (const float*)d_in[5];
  const float* rv1 = (const float*)d_in[6];
  const float* W2  = (const float*)d_in[7];
  const float* b2  = (const float*)d_in[8];
  const float* g2  = (const float*)d_in[9];
  const float* be2 = (const float*)d_in[10];
  const float* rm2 = (const float*)d_in[11];
  const float* rv2 = (const float*)d_in[12];
  const float* W3  = (const float*)d_in[13];
  const float* b3  = (const float*)d_in[14];
  const float* CB  = (const float*)d_in[15];
  const float* W4  = (const float*)d_in[16];
  const float* b4  = (const float*)d_in[17];
  const float* g3  = (const float*)d_in[18];
  const float* be3 = (const float*)d_in[19];
  const float* rm3 = (const float*)d_in[20];
  const float* rv3 = (const float*)d_in[21];
  const float* W5  = (const float*)d_in[22];
  const float* b5  = (const float*)d_in[23];
  const float* g4  = (const float*)d_in[24];
  const float* be4 = (const float*)d_in[25];
  const float* rm4 = (const float*)d_in[26];
  const float* rv4 = (const float*)d_in[27];
  const float* W6  = (const float*)d_in[28];
  const float* b6  = (const float*)d_in[29];

  char* w = (char*)d_ws;                       // total ~24.6 MiB
  // Eb + cq/cj alias the h-region (dead during VQ).
  ushort* Eb   = (ushort*)(w + 0);             // per-book bf16 codebook (frag layout), 2 MiB
  float*  cq   = (float*) (w + 2097152);       // 8192x16, 512 KiB
  int*    cj   = (int*)   (w + 2621440);       // 8192x16, 512 KiB
  ushort* rhi  = (ushort*)(w + 12582912);      // residual split, 2 MiB
  ushort* rlo  = (ushort*)(w + 14680064);      // 2 MiB
  float*  res  = (float*) (w + 16777216);      // 4 MiB
  float*  zq   = (float*) (w + 20971520);      // 4 MiB
  float*  hen  = (float*) (w + 25165824);      // per-book half-norms, 32 KiB
  float*  s1   = (float*) (w + 25198592);
  float*  t1   = (float*) (w + 25199104);
  float*  s2   = (float*) (w + 25199616);
  float*  t2   = (float*) (w + 25200640);
  float*  s3   = (float*) (w + 25201664);
  float*  t3   = (float*) (w + 25202688);
  float*  s4   = (float*) (w + 25203712);
  float*  t4   = (float*) (w + 25204224);
  ushort* W1fh = (ushort*)(w + 25204736);
  ushort* W2fh = (ushort*)(w + 25270272);
  ushort* W3fh = (ushort*)(w + 25335808);
  ushort* W4fh = (ushort*)(w + 25401344);
  ushort* W5fh = (ushort*)(w + 25466880);
  ushort* W6fh = (ushort*)(w + 25532416);
  ushort* W1fl = (ushort*)(w + 25597952);
  ushort* W2fl = (ushort*)(w + 25663488);
  ushort* W3fl = (ushort*)(w + 25729024);      // end ~24.6 MiB

  float* xhat  = (float*)d_out;                // [8192,256] fp32
  float* res_s = xhat + 2097152;               // [8,8192,128] fp32
  float* ce_s  = res_s + 8388608;              // [8,8192,128] fp32

  // prep: weights -> frag layout + BN fold
  k_prep<<<769, 256, 0, stream>>>(W1, W2, W3, W4, W5, W6,
                                  W1fh, W1fl, W2fh, W2fl, W3fh, W3fl,
                                  W4fh, W5fh, W6fh,
                                  g1,be1,rm1,rv1, g2,be2,rm2,rv2,
                                  g3,be3,rm3,rv3, g4,be4,rm4,rv4,
                                  s1,t1,s2,t2,s3,t3,s4,t4);

  // fused encoder
  k_encoder<<<512, 256, 0, stream>>>(x, W1fh, W1fl, W2fh, W2fl, W3fh, W3fl,
                                     b1, s1, t1, b2, s2, t2, b3,
                                     rhi, rlo, res, zq);

  // residual VQ over 8 books (ebook for book m+1 fused into update(m))
  k_ebook<<<2048, 256, 0, stream>>>(CB, Eb, hen);
  for (int m = 0; m < 8; m++){
    const float* Ef = CB + (size_t)m * 1048576;
    k_vq_argmin<<<1024, 256, 0, stream>>>(rhi, rlo, Eb, hen, cq, cj);
    if (m < 7){
      k_vq_update<false><<<2048, 256, 0, stream>>>(cq, cj, Ef, Ef + 1048576, Eb, hen,
                                                   res, zq, rhi, rlo,
                                                   res_s + (size_t)m * 1048576,
                                                   ce_s  + (size_t)m * 1048576);
    } else {
      k_vq_update<true><<<2048, 256, 0, stream>>>(cq, cj, Ef, nullptr, Eb, hen,
                                                  res, zq, rhi, rlo,
                                                  res_s + (size_t)m * 1048576,
                                                  ce_s  + (size_t)m * 1048576);
    }
  }

  // fused decoder (rhi/rlo hold split(di) from update<LAST>)
  k_decoder<<<512, 256, 0, stream>>>(rhi, rlo, W4fh, W5fh, W6fh,
                                     b4, s3, t3, b5, s4, t4, b6, xhat);
}

// Round 3
// 445.825 us; speedup vs baseline: 1.5097x; 1.1999x over previous
//
#include <hip/hip_runtime.h>
#include <hip/hip_bf16.h>

// ResidualVQVAE forward, FP32 in / FP32 out.
// R11: argmin goes hi-only (1 MFMA per K-step instead of 2). Score noise from
// dropping rlo (~2.7e-7) matches the already-accepted bf16-codebook rounding noise
// (~2.4e-7); pick flips stay bounded by max|e_a-e_b| ~ 2.4e-4/elem. Freed VGPRs fund
// a true 2-group-deep B prefetch (~118 VGPR < 128 cap, 4 waves/SIMD, no LDS).
// zq eliminated (di = ze - res_final, ze re-read from res_s[0]); rlo dropped from
// the VQ loop (only update<LAST> emits the decoder's dlo). 20 -> 19 dispatches.

typedef __bf16 bf16x8 __attribute__((ext_vector_type(8)));
typedef float  f32x4  __attribute__((ext_vector_type(4)));
typedef unsigned short ushort8v __attribute__((ext_vector_type(8)));

#define MFMA16(a,b,c) __builtin_amdgcn_mfma_f32_16x16x32_bf16((a),(b),(c),0,0,0)

__device__ __forceinline__ float b2f(ushort u){ return __uint_as_float(((unsigned)u) << 16); }
__device__ __forceinline__ ushort f2b_rne(float x){
  unsigned u = __float_as_uint(x);
  return (ushort)((u + 0x7fffu + ((u >> 16) & 1u)) >> 16);
}

// convert 8 consecutive fp32 -> bf16 hi/lo fragment pair
__device__ __forceinline__ void cvt8(const float* p, bf16x8& h8, bf16x8& l8){
  f32x4 v0 = *(const f32x4*)p;
  f32x4 v1 = *(const f32x4*)(p + 4);
  ushort8v uh, ul;
  #pragma unroll
  for (int i = 0; i < 4; i++){
    float a = v0[i]; ushort h = f2b_rne(a); uh[i] = h;     ul[i]     = f2b_rne(a - b2f(h));
    float b = v1[i]; ushort g = f2b_rne(b); uh[i + 4] = g; ul[i + 4] = f2b_rne(b - b2f(g));
  }
  h8 = __builtin_bit_cast(bf16x8, uh);
  l8 = __builtin_bit_cast(bf16x8, ul);
}

// one 16x16 output-column-tile dot product (hi/lo compensated A, hi(+lo) B)
template<int KK, int NN, bool HAS_BLO>
__device__ __forceinline__ f32x4 dotct(const bf16x8* ah, const bf16x8* al,
                                       const ushort* __restrict__ Bfh,
                                       const ushort* __restrict__ Bfl,
                                       int ct, int L){
  constexpr int KS = KK / 32, CT = NN / 16;
  f32x4 acc = {0.f, 0.f, 0.f, 0.f};
  #pragma unroll
  for (int ks = 0; ks < KS; ks++){
    int bo = ((ks * CT + ct) * 64 + L) * 8;
    bf16x8 bh = *(const bf16x8*)(Bfh + bo);
    acc = MFMA16(ah[ks], bh, acc);
    acc = MFMA16(al[ks], bh, acc);
    if constexpr (HAS_BLO){
      bf16x8 bl = *(const bf16x8*)(Bfl + bo);
      acc = MFMA16(ah[ks], bl, acc);
    }
  }
  return acc;
}

// ---------------- prep: weight swizzle + BN fold ------------------------------------------
__device__ __forceinline__ void swz_body(const float* __restrict__ Wm, ushort* __restrict__ Wfh,
                                         ushort* __restrict__ Wfl, int N, int b){
  int gid = b * 256 + threadIdx.x;          // all weights are 32768 elems (128 blocks)
  int k = gid / N, n = gid - k * N;
  int kt = k >> 5, kr = k & 31, nt = n >> 4, nr = n & 15;
  int lane = (kr >> 3) * 16 + nr, tt = kr & 7;
  int o = (((kt * (N >> 4)) + nt) * 64 + lane) * 8 + tt;
  float v = Wm[gid];
  ushort h = f2b_rne(v);
  Wfh[o] = h;
  if (Wfl) Wfl[o] = f2b_rne(v - b2f(h));
}

__global__ __launch_bounds__(256) void k_prep(
    const float* __restrict__ W1, const float* __restrict__ W2, const float* __restrict__ W3,
    const float* __restrict__ W4, const float* __restrict__ W5, const float* __restrict__ W6,
    ushort* W1fh, ushort* W1fl, ushort* W2fh, ushort* W2fl, ushort* W3fh, ushort* W3fl,
    ushort* W4fh, ushort* W5fh, ushort* W6fh,
    const float* g1,const float* be1,const float* rm1,const float* rv1,
    const float* g2,const float* be2,const float* rm2,const float* rv2,
    const float* g3,const float* be3,const float* rm3,const float* rv3,
    const float* g4,const float* be4,const float* rm4,const float* rv4,
    float* s1,float* t1,float* s2,float* t2,float* s3,float* t3,float* s4,float* t4)
{
  int b = blockIdx.x;
  if (b < 768){
    if      (b < 128) swz_body(W1, W1fh, W1fl, 128, b);
    else if (b < 256) swz_body(W2, W2fh, W2fl, 256, b - 128);
    else if (b < 384) swz_body(W3, W3fh, W3fl, 128, b - 256);
    else if (b < 512) swz_body(W4, W4fh, nullptr, 256, b - 384);
    else if (b < 640) swz_body(W5, W5fh, nullptr, 128, b - 512);
    else              swz_body(W6, W6fh, nullptr, 256, b - 640);
  } else {
    int t = threadIdx.x;
    if (t < 128){
      float sa = g1[t] / sqrtf(rv1[t] + 1e-5f);
      s1[t] = sa; t1[t] = be1[t] - rm1[t] * sa;
      float sb = g4[t] / sqrtf(rv4[t] + 1e-5f);
      s4[t] = sb; t4[t] = be4[t] - rm4[t] * sb;
    }
    if (t < 256){
      float sa = g2[t] / sqrtf(rv2[t] + 1e-5f);
      s2[t] = sa; t2[t] = be2[t] - rm2[t] * sa;
      float sb = g3[t] / sqrtf(rv3[t] + 1e-5f);
      s3[t] = sb; t3[t] = be3[t] - rm3[t] * sb;
    }
  }
}

// ---------------- fused encoder: x -> (bn relu gemm)x2 -> gemm -> res/rhi -----------------
__global__ __launch_bounds__(256) void k_encoder(
    const float* __restrict__ x,
    const ushort* __restrict__ W1fh, const ushort* __restrict__ W1fl,
    const ushort* __restrict__ W2fh, const ushort* __restrict__ W2fl,
    const ushort* __restrict__ W3fh, const ushort* __restrict__ W3fl,
    const float* __restrict__ b1, const float* __restrict__ s1, const float* __restrict__ t1,
    const float* __restrict__ b2, const float* __restrict__ s2, const float* __restrict__ t2,
    const float* __restrict__ b3,
    ushort* __restrict__ rhi, float* __restrict__ res)
{
  __shared__ __align__(16) float sA[16 * 260];   // 16 x 256 stage (+4 pad)
  __shared__ __align__(16) float sB[16 * 132];   // 16 x 128 stage (+4 pad)
  int tid = threadIdx.x;
  int wv = tid >> 6, L = tid & 63;
  int qd = L >> 4, c16 = L & 15;
  int row0 = blockIdx.x * 16;

  bf16x8 a1h[8], a1l[8];
  #pragma unroll
  for (int ks = 0; ks < 8; ks++)
    cvt8(x + (row0 + c16) * 256 + ks * 32 + qd * 8, a1h[ks], a1l[ks]);

  #pragma unroll
  for (int u = 0; u < 2; u++){
    int ct = wv * 2 + u;
    f32x4 acc = dotct<256,128,true>(a1h, a1l, W1fh, W1fl, ct, L);
    int col = ct * 16 + c16;
    float bia = b1[col], sc = s1[col], sh = t1[col];
    #pragma unroll
    for (int i = 0; i < 4; i++){
      float v = (acc[i] + bia) * sc + sh;
      sB[(qd * 4 + i) * 132 + col] = fmaxf(v, 0.f);
    }
  }
  __syncthreads();

  bf16x8 a2h[4], a2l[4];
  #pragma unroll
  for (int ks = 0; ks < 4; ks++)
    cvt8(sB + c16 * 132 + ks * 32 + qd * 8, a2h[ks], a2l[ks]);

  #pragma unroll
  for (int u = 0; u < 4; u++){
    int ct = wv * 4 + u;
    f32x4 acc = dotct<128,256,true>(a2h, a2l, W2fh, W2fl, ct, L);
    int col = ct * 16 + c16;
    float bia = b2[col], sc = s2[col], sh = t2[col];
    #pragma unroll
    for (int i = 0; i < 4; i++){
      float v = (acc[i] + bia) * sc + sh;
      sA[(qd * 4 + i) * 260 + col] = fmaxf(v, 0.f);
    }
  }
  __syncthreads();

  bf16x8 a3h[8], a3l[8];
  #pragma unroll
  for (int ks = 0; ks < 8; ks++)
    cvt8(sA + c16 * 260 + ks * 32 + qd * 8, a3h[ks], a3l[ks]);

  #pragma unroll
  for (int u = 0; u < 2; u++){
    int ct = wv * 2 + u;
    f32x4 acc = dotct<256,128,true>(a3h, a3l, W3fh, W3fl, ct, L);
    int col = ct * 16 + c16;
    float bia = b3[col];
    #pragma unroll
    for (int i = 0; i < 4; i++){
      int row = row0 + qd * 4 + i;
      float v = acc[i] + bia;
      int o = row * 128 + col;
      res[o] = v;
      rhi[o] = f2b_rne(v);
    }
  }
}

// ---------------- fused decoder: di -> (bn relu gemm)x2 -> gemm -> xhat -------------------
__global__ __launch_bounds__(256) void k_decoder(
    const ushort* __restrict__ dhi, const ushort* __restrict__ dlo,
    const ushort* __restrict__ W4fh, const ushort* __restrict__ W5fh,
    const ushort* __restrict__ W6fh,
    const float* __restrict__ b4, const float* __restrict__ s3, const float* __restrict__ t3,
    const float* __restrict__ b5, const float* __restrict__ s4, const float* __restrict__ t4,
    const float* __restrict__ b6,
    float* __restrict__ xhat)
{
  __shared__ __align__(16) float sA[16 * 260];
  __shared__ __align__(16) float sB[16 * 132];
  int tid = threadIdx.x;
  int wv = tid >> 6, L = tid & 63;
  int qd = L >> 4, c16 = L & 15;
  int row0 = blockIdx.x * 16;

  bf16x8 a1h[4], a1l[4];
  #pragma unroll
  for (int ks = 0; ks < 4; ks++){
    int off = (row0 + c16) * 128 + ks * 32 + qd * 8;
    a1h[ks] = *(const bf16x8*)(dhi + off);
    a1l[ks] = *(const bf16x8*)(dlo + off);
  }

  #pragma unroll
  for (int u = 0; u < 4; u++){
    int ct = wv * 4 + u;
    f32x4 acc = dotct<128,256,false>(a1h, a1l, W4fh, nullptr, ct, L);
    int col = ct * 16 + c16;
    float bia = b4[col], sc = s3[col], sh = t3[col];
    #pragma unroll
    for (int i = 0; i < 4; i++){
      float v = (acc[i] + bia) * sc + sh;
      sA[(qd * 4 + i) * 260 + col] = fmaxf(v, 0.f);
    }
  }
  __syncthreads();

  bf16x8 a2h[8], a2l[8];
  #pragma unroll
  for (int ks = 0; ks < 8; ks++)
    cvt8(sA + c16 * 260 + ks * 32 + qd * 8, a2h[ks], a2l[ks]);

  #pragma unroll
  for (int u = 0; u < 2; u++){
    int ct = wv * 2 + u;
    f32x4 acc = dotct<256,128,false>(a2h, a2l, W5fh, nullptr, ct, L);
    int col = ct * 16 + c16;
    float bia = b5[col], sc = s4[col], sh = t4[col];
    #pragma unroll
    for (int i = 0; i < 4; i++){
      float v = (acc[i] + bia) * sc + sh;
      sB[(qd * 4 + i) * 132 + col] = fmaxf(v, 0.f);
    }
  }
  __syncthreads();

  bf16x8 a3h[4], a3l[4];
  #pragma unroll
  for (int ks = 0; ks < 4; ks++)
    cvt8(sB + c16 * 132 + ks * 32 + qd * 8, a3h[ks], a3l[ks]);

  #pragma unroll
  for (int u = 0; u < 4; u++){
    int ct = wv * 4 + u;
    f32x4 acc = dotct<128,256,false>(a3h, a3l, W6fh, nullptr, ct, L);
    int col = ct * 16 + c16;
    float bia = b6[col];
    #pragma unroll
    for (int i = 0; i < 4; i++)
      xhat[(row0 + qd * 4 + i) * 256 + col] = acc[i] + bia;
  }
}

// ---------------- per-book: codebook -> bf16 MFMA B-fragment layout + half-norms ----------
__device__ __forceinline__ void ebook_body(const float* __restrict__ Ef, ushort* __restrict__ Eb,
                                           float* __restrict__ hen, int code, int L){
  float2 e2 = *(const float2*)(Ef + code * 128 + L * 2);
  ushort h0 = f2b_rne(e2.x), h1 = f2b_rne(e2.y);
  int d = L * 2;
  int o = ((((code >> 4) * 4 + (d >> 5)) * 4 + ((d >> 3) & 3)) * 16 + (code & 15)) * 8 + (d & 7);
  *(unsigned*)(Eb + o) = (unsigned)h0 | ((unsigned)h1 << 16);
  float eh0 = b2f(h0), eh1 = b2f(h1);
  float s = eh0 * eh0 + eh1 * eh1;
  #pragma unroll
  for (int mask = 1; mask <= 32; mask <<= 1) s += __shfl_xor(s, mask);
  if (L == 0) hen[code] = 0.5f * s;
}

__global__ __launch_bounds__(256) void k_ebook(const float* __restrict__ Ef,
                                               ushort* __restrict__ Eb, float* __restrict__ hen){
  ebook_body(Ef, Eb, hen, blockIdx.x * 4 + (threadIdx.x >> 6), threadIdx.x & 63);
}

// ---------------- VQ: hi-only distance + argmax(r.e - 0.5||e||^2) -------------------------
// 8 MFMA/group (hi only); A = 32 regs -> 2-group-deep B prefetch fits ~118 VGPR,
// 4 waves/SIMD at launch_bounds(256,4), 0 LDS, no barriers.
__global__ __launch_bounds__(256, 4) void k_vq_argmin(
  const ushort* __restrict__ Rhi,
  const ushort* __restrict__ Eb, const float* __restrict__ hen,
  float* __restrict__ cq, int* __restrict__ cj)
{
  int rb = blockIdx.x & 63, ch = blockIdx.x >> 6;
  int tid = threadIdx.x;
  int wv = tid >> 6, L = tid & 63;
  int qd = L >> 4, c16 = L & 15;
  int row0 = rb * 128 + wv * 32;

  // resident A fragments: 32 rows, hi only (32 VGPRs)
  bf16x8 ah[2][4];
  #pragma unroll
  for (int t = 0; t < 2; t++){
    int r = row0 + t * 16 + c16;
    #pragma unroll
    for (int ks = 0; ks < 4; ks++)
      ah[t][ks] = *(const bf16x8*)(Rhi + r * 128 + ks * 32 + qd * 8);
  }
  float best[2][4]; int bj[2][4];
  #pragma unroll
  for (int t = 0; t < 2; t++)
    #pragma unroll
    for (int i = 0; i < 4; i++){ best[t][i] = -3.0e38f; bj[t][i] = 0; }

  const ushort* eb = Eb + (size_t)ch * 65536 + L * 8;   // chunk base, frag layout
  const float*  hb = hen + ch * 512 + c16;
  int jb = ch * 512 + c16;

  // 2-group-deep prefetch
  bf16x8 bA0 = *(const bf16x8*)(eb + 0),    bA1 = *(const bf16x8*)(eb + 512),
         bA2 = *(const bf16x8*)(eb + 1024), bA3 = *(const bf16x8*)(eb + 1536);
  bf16x8 bB0 = *(const bf16x8*)(eb + 2048 + 0),    bB1 = *(const bf16x8*)(eb + 2048 + 512),
         bB2 = *(const bf16x8*)(eb + 2048 + 1024), bB3 = *(const bf16x8*)(eb + 2048 + 1536);
  float hA = hb[0], hB = hb[16];

  #pragma unroll 1
  for (int g = 0; g < 32; g += 2){
    // ---- group g (bA) ----
    f32x4 accA0 = {0.f,0.f,0.f,0.f}, accA1 = {0.f,0.f,0.f,0.f};
    __builtin_amdgcn_s_setprio(1);
    accA0 = MFMA16(ah[0][0], bA0, accA0); accA0 = MFMA16(ah[0][1], bA1, accA0);
    accA0 = MFMA16(ah[0][2], bA2, accA0); accA0 = MFMA16(ah[0][3], bA3, accA0);
    accA1 = MFMA16(ah[1][0], bA0, accA1); accA1 = MFMA16(ah[1][1], bA1, accA1);
    accA1 = MFMA16(ah[1][2], bA2, accA1); accA1 = MFMA16(ah[1][3], bA3, accA1);
    __builtin_amdgcn_s_setprio(0);
    // prefetch group g+2 into bA (clamped; duplicate harmless)
    {
      int gp = (g + 2 < 32) ? g + 2 : 30;
      const ushort* ebp = eb + gp * 2048;
      bA0 = *(const bf16x8*)(ebp + 0);    bA1 = *(const bf16x8*)(ebp + 512);
      bA2 = *(const bf16x8*)(ebp + 1024); bA3 = *(const bf16x8*)(ebp + 1536);
      float hA2 = hb[gp * 16];
      int jc = jb + g * 16;
      #pragma unroll
      for (int i = 0; i < 4; i++){
        float q0 = accA0[i] - hA;
        if (q0 > best[0][i]){ best[0][i] = q0; bj[0][i] = jc; }
        float q1 = accA1[i] - hA;
        if (q1 > best[1][i]){ best[1][i] = q1; bj[1][i] = jc; }
      }
      hA = hA2;
    }
    // ---- group g+1 (bB) ----
    f32x4 accB0 = {0.f,0.f,0.f,0.f}, accB1 = {0.f,0.f,0.f,0.f};
    __builtin_amdgcn_s_setprio(1);
    accB0 = MFMA16(ah[0][0], bB0, accB0); accB0 = MFMA16(ah[0][1], bB1, accB0);
    accB0 = MFMA16(ah[0][2], bB2, accB0); accB0 = MFMA16(ah[0][3], bB3, accB0);
    accB1 = MFMA16(ah[1][0], bB0, accB1); accB1 = MFMA16(ah[1][1], bB1, accB1);
    accB1 = MFMA16(ah[1][2], bB2, accB1); accB1 = MFMA16(ah[1][3], bB3, accB1);
    __builtin_amdgcn_s_setprio(0);
    // prefetch group g+3 into bB (clamped)
    {
      int gq = (g + 3 < 32) ? g + 3 : 31;
      const ushort* ebq = eb + gq * 2048;
      bB0 = *(const bf16x8*)(ebq + 0);    bB1 = *(const bf16x8*)(ebq + 512);
      bB2 = *(const bf16x8*)(ebq + 1024); bB3 = *(const bf16x8*)(ebq + 1536);
      float hB2 = hb[gq * 16];
      int jc = jb + (g + 1) * 16;
      #pragma unroll
      for (int i = 0; i < 4; i++){
        float q0 = accB0[i] - hB;
        if (q0 > best[0][i]){ best[0][i] = q0; bj[0][i] = jc; }
        float q1 = accB1[i] - hB;
        if (q1 > best[1][i]){ best[1][i] = q1; bj[1][i] = jc; }
      }
      hB = hB2;
    }
  }

  // cross-lane reduce over the 16 code-columns, ties -> smaller j
  #pragma unroll
  for (int mask = 1; mask <= 8; mask <<= 1){
    #pragma unroll
    for (int t = 0; t < 2; t++)
      #pragma unroll
      for (int i = 0; i < 4; i++){
        float ob = __shfl_xor(best[t][i], mask);
        int   oj = __shfl_xor(bj[t][i], mask);
        if (ob > best[t][i] || (ob == best[t][i] && oj < bj[t][i])){ best[t][i] = ob; bj[t][i] = oj; }
      }
  }
  if (c16 == 0){
    #pragma unroll
    for (int t = 0; t < 2; t++)
      #pragma unroll
      for (int i = 0; i < 4; i++){
        int r = row0 + t * 16 + qd * 4 + i;
        cq[r * 16 + ch] = best[t][i];
        cj[r * 16 + ch] = bj[t][i];
      }
  }
}

// ---------------- VQ: combine chunk candidates, emit res_s/ce_s, update, + next ebook -----
// !LAST: res/rhi updated for next book; next codebook converted (Eb already consumed).
// LAST: di = ze - res_final (ze read from res_s[0]); emits decoder's dhi/dlo.
template<bool LAST>
__global__ __launch_bounds__(256) void k_vq_update(
  const float* __restrict__ cq, const int* __restrict__ cj,
  const float* __restrict__ Ef, const float* __restrict__ Efn,
  ushort* __restrict__ Eb, float* __restrict__ hen,
  float* __restrict__ res, const float* __restrict__ ze_s,
  ushort* __restrict__ rhi, ushort* __restrict__ rlo,
  float* __restrict__ res_s, float* __restrict__ ce_s)
{
  int idx = blockIdx.x * 4 + (threadIdx.x >> 6);
  int L = threadIdx.x & 63;
  int c = L & 15;
  float bq = cq[idx * 16 + c]; int bi = cj[idx * 16 + c];
  #pragma unroll
  for (int mask = 1; mask <= 8; mask <<= 1){
    float ob = __shfl_xor(bq, mask);
    int   oj = __shfl_xor(bi, mask);
    if (ob > bq || (ob == bq && oj < bi)){ bq = ob; bi = oj; }
  }
  int o = idx * 128 + L * 2;
  float2 ce = *(const float2*)(Ef + bi * 128 + L * 2);   // fp32 codebook row
  float2 r2 = *(const float2*)(res + o);
  *(float2*)(res_s + o) = r2;
  *(float2*)(ce_s + o) = ce;
  float rn0 = r2.x - ce.x, rn1 = r2.y - ce.y;
  if constexpr (LAST){
    float2 z2 = *(const float2*)(ze_s + o);              // ze from res_s[0]
    float d0 = z2.x - rn0, d1 = z2.y - rn1;              // di = ze - res_final
    ushort h0 = f2b_rne(d0), h1 = f2b_rne(d1);
    *(unsigned*)(rhi + o) = (unsigned)h0 | ((unsigned)h1 << 16);
    ushort l0 = f2b_rne(d0 - b2f(h0)), l1 = f2b_rne(d1 - b2f(h1));
    *(unsigned*)(rlo + o) = (unsigned)l0 | ((unsigned)l1 << 16);
  } else {
    res[o] = rn0; res[o + 1] = rn1;
    ushort h0 = f2b_rne(rn0), h1 = f2b_rne(rn1);
    *(unsigned*)(rhi + o) = (unsigned)h0 | ((unsigned)h1 << 16);
    ebook_body(Efn, Eb, hen, idx, L);
  }
}

extern "C" void kernel_launch(void* const* d_in, const int* in_sizes, int n_in,
                              void* d_out, int out_size, void* d_ws, size_t ws_size,
                              hipStream_t stream)
{
  const float* x   = (const float*)d_in[0];
  const float* W1  = (const float*)d_in[1];
  const float* b1  = (const float*)d_in[2];
  const float* g1  = (const float*)d_in[3];
  const float* be1 = (const float*)d_in[4];
  const float* rm1 = (const float*)d_in[5];
  const float* rv1 = (const float*)d_in[6];
  const float* W2  = (const float*)d_in[7];
  const float* b2  = (const float*)d_in[8];
  const float* g2  = (const float*)d_in[9];
  const float* be2 = (const float*)d_in[10];
  const float* rm2 = (const float*)d_in[11];
  const float* rv2 = (const float*)d_in[12];
  const float* W3  = (const float*)d_in[13];
  const float* b3  = (const float*)d_in[14];
  const float* CB  = (const float*)d_in[15];
  const float* W4  = (const float*)d_in[16];
  const float* b4  = (const float*)d_in[17];
  const float* g3  = (const float*)d_in[18];
  const float* be3 = (const float*)d_in[19];
  const float* rm3 = (const float*)d_in[20];
  const float* rv3 = (const float*)d_in[21];
  const float* W5  = (const float*)d_in[22];
  const float* b5  = (const float*)d_in[23];
  const float* g4  = (const float*)d_in[24];
  const float* be4 = (const float*)d_in[25];
  const float* rm4 = (const float*)d_in[26];
  const float* rv4 = (const float*)d_in[27];
  const float* W6  = (const float*)d_in[28];
  const float* b6  = (const float*)d_in[29];

  char* w = (char*)d_ws;
  ushort* Eb   = (ushort*)(w + 0);             // per-book bf16 codebook (frag layout), 2 MiB
  float*  cq   = (float*) (w + 2097152);       // 8192x16, 512 KiB
  int*    cj   = (int*)   (w + 2621440);       // 8192x16, 512 KiB
  ushort* rhi  = (ushort*)(w + 12582912);      // residual hi split, 2 MiB
  ushort* rlo  = (ushort*)(w + 14680064);      // decoder dlo, 2 MiB
  float*  res  = (float*) (w + 16777216);      // 4 MiB
  float*  hen  = (float*) (w + 25165824);      // per-book half-norms, 32 KiB
  float*  s1   = (float*) (w + 25198592);
  float*  t1   = (float*) (w + 25199104);
  float*  s2   = (float*) (w + 25199616);
  float*  t2   = (float*) (w + 25200640);
  float*  s3   = (float*) (w + 25201664);
  float*  t3   = (float*) (w + 25202688);
  float*  s4   = (float*) (w + 25203712);
  float*  t4   = (float*) (w + 25204224);
  ushort* W1fh = (ushort*)(w + 25204736);
  ushort* W2fh = (ushort*)(w + 25270272);
  ushort* W3fh = (ushort*)(w + 25335808);
  ushort* W4fh = (ushort*)(w + 25401344);
  ushort* W5fh = (ushort*)(w + 25466880);
  ushort* W6fh = (ushort*)(w + 25532416);
  ushort* W1fl = (ushort*)(w + 25597952);
  ushort* W2fl = (ushort*)(w + 25663488);
  ushort* W3fl = (ushort*)(w + 25729024);

  float* xhat  = (float*)d_out;                // [8192,256] fp32
  float* res_s = xhat + 2097152;               // [8,8192,128] fp32
  float* ce_s  = res_s + 8388608;              // [8,8192,128] fp32

  k_prep<<<769, 256, 0, stream>>>(W1, W2, W3, W4, W5, W6,
                                  W1fh, W1fl, W2fh, W2fl, W3fh, W3fl,
                                  W4fh, W5fh, W6fh,
                                  g1,be1,rm1,rv1, g2,be2,rm2,rv2,
                                  g3,be3,rm3,rv3, g4,be4,rm4,rv4,
                                  s1,t1,s2,t2,s3,t3,s4,t4);

  k_encoder<<<512, 256, 0, stream>>>(x, W1fh, W1fl, W2fh, W2fl, W3fh, W3fl,
                                     b1, s1, t1, b2, s2, t2, b3,
                                     rhi, res);

  // residual VQ over 8 books (ebook for book m+1 fused into update(m))
  k_ebook<<<2048, 256, 0, stream>>>(CB, Eb, hen);
  for (int m = 0; m < 8; m++){
    const float* Ef = CB + (size_t)m * 1048576;
    k_vq_argmin<<<1024, 256, 0, stream>>>(rhi, Eb, hen, cq, cj);
    if (m < 7){
      k_vq_update<false><<<2048, 256, 0, stream>>>(cq, cj, Ef, Ef + 1048576, Eb, hen,
                                                   res, nullptr, rhi, nullptr,
                                                   res_s + (size_t)m * 1048576,
                                                   ce_s  + (size_t)m * 1048576);
    } else {
      k_vq_update<true><<<2048, 256, 0, stream>>>(cq, cj, Ef, nullptr, Eb, hen,
                                                  res, res_s /*ze = res_s[0]*/, rhi, rlo,
                                                  res_s + (size_t)m * 1048576,
                                                  ce_s  + (size_t)m * 1048576);
    }
  }

  // fused decoder (rhi/rlo hold split(di) from update<LAST>)
  k_decoder<<<512, 256, 0, stream>>>(rhi, rlo, W4fh, W5fh, W6fh,
                                     b4, s3, t3, b5, s4, t4, b6, xhat);
}